// Round 1
// baseline (70.259 us; speedup 1.0000x reference)
//
#include <hip/hip_runtime.h>
#include <hip/hip_bf16.h>

// B=8, Lq=2048, Lk=2048, D=256. out = softmax(mask? sq_i+sk_j : -1e9) @ V.
// sq_i cancels in softmax => out[i] = (mask[i]·(e*V)) / (mask[i]·e), e=exp(K·w).
// Stage 1: e + evT (bf16, transposed K-major). Stage 2: bf16 MFMA masked GEMM.
// Workspace: evT 8*256*2048*2 = 8 MB, e 8*2048*4 = 64 KB.

#define NB 8
#define LQ 2048
#define LK 2048
#define DD 256

typedef __attribute__((ext_vector_type(8))) short short8v;
typedef __attribute__((ext_vector_type(8))) unsigned short ushort8v;
typedef __attribute__((ext_vector_type(4))) float f32x4;

__device__ inline unsigned short f2bf(float x) {
  __hip_bfloat16 h = __float2bfloat16(x);
  union { __hip_bfloat16 h; unsigned short u; } cv;
  cv.h = h;
  return cv.u;
}

// ---------------- Stage 1: e = exp(K·w); evT[b][d][j] = bf16(e_j * V[j][d]) ----
__global__ __launch_bounds__(256) void bah_precompute(
    const float* __restrict__ key, const float* __restrict__ value,
    const float* __restrict__ w, unsigned short* __restrict__ evT,
    float* __restrict__ e_out)
{
  __shared__ float w_s[DD];
  __shared__ unsigned short t_s[64][DD];   // [j_local][d] transpose buffer, 32 KB

  const int t = threadIdx.x;
  const int lane = t & 63;
  const int wid = t >> 6;                  // 0..3
  const int blk = blockIdx.x;
  const int b = blk & 7;                   // batch -> XCD locality heuristic
  const int j0 = (blk >> 3) * 64;

  w_s[t] = w[t];
  __syncthreads();

  const float4* wv = reinterpret_cast<const float4*>(w_s);
  const float4 wv4 = wv[lane];

  // one wave per row: 64 lanes * float4 = full 256-elem row
  for (int it = 0; it < 16; ++it) {
    const int r = it * 4 + wid;
    const size_t row = (size_t)b * LK + (j0 + r);
    const float4 kv = reinterpret_cast<const float4*>(key + row * DD)[lane];
    float s = kv.x * wv4.x + kv.y * wv4.y + kv.z * wv4.z + kv.w * wv4.w;
#pragma unroll
    for (int off = 32; off; off >>= 1) s += __shfl_xor(s, off);
    const float e = __expf(s);             // no max-shift needed: |s| small
    if (lane == 0) e_out[row] = e;
    const float4 vv = reinterpret_cast<const float4*>(value + row * DD)[lane];
    ushort4 u;
    u.x = f2bf(e * vv.x);
    u.y = f2bf(e * vv.y);
    u.z = f2bf(e * vv.z);
    u.w = f2bf(e * vv.w);
    *reinterpret_cast<ushort4*>(&t_s[r][lane * 4]) = u;
  }
  __syncthreads();

  // transposed write-out: thread t owns d = t, gathers 64 j's, coalesced 16B stores
  const int d = t;
  unsigned short* dst = evT + ((size_t)b * DD + d) * LK + j0;
#pragma unroll
  for (int s8 = 0; s8 < 8; ++s8) {
    ushort8v val;
#pragma unroll
    for (int c = 0; c < 8; ++c) val[c] = t_s[s8 * 8 + c][d];
    *reinterpret_cast<ushort8v*>(dst + s8 * 8) = val;
  }
}

// ---------------- Stage 2: out[i][d] = (mask[i]·evT_d) / (mask[i]·e) ----------
// BM=64, BN=256(full), BK=64. 8 waves: 2(M) x 4(N), wave tile 32x64.
// LDS tiles XOR-swizzled: ushort index k ^= (row&7)*8 -> conflict-free ds_read_b128.
__global__ __launch_bounds__(512) void bah_gemm(
    const int* __restrict__ mask, const unsigned short* __restrict__ evT,
    const float* __restrict__ e_arr, float* __restrict__ out)
{
  __shared__ unsigned short A_s[64 * 64];   // mask tile as bf16 (8 KB)
  __shared__ unsigned short B_s[DD * 64];   // evT tile [d][k] (32 KB)
  __shared__ float denom_s[64];

  const int t = threadIdx.x;
  const int lane = t & 63;
  const int wid = t >> 6;
  const int wm = wid >> 2;                  // 0..1
  const int wn = wid & 3;                   // 0..3

  const int blk = blockIdx.x;
  const int b = blk & 7;
  const int i0 = (blk >> 3) * 64;

  // A staging: thread -> row sr, two 4-int chunks (fully coalesced 128B/8-lanes)
  const int sr = t >> 3;
  const int c0 = (t & 7) * 4;
  const int swA = (sr & 7) * 8;
  const int* mrow = mask + ((size_t)b * LQ + (i0 + sr)) * LK;
  const float* ebase = e_arr + (size_t)b * LK;

  // B staging: thread -> d-row bd, 32 ushorts starting at bj
  const int bd = t >> 1;
  const int bj = (t & 1) * 32;
  const int swB = (bd & 7) * 8;
  const unsigned short* evrow = evT + ((size_t)b * DD + bd) * LK;

  f32x4 acc[2][4] = {};
  float dpart = 0.f;

  for (int k0 = 0; k0 < LK; k0 += 64) {
    __syncthreads();
    // ---- stage A: mask -> bf16 {0,1}; fold denominator on the VALU ----
    const int4 m0 = *reinterpret_cast<const int4*>(mrow + k0 + c0);
    const int4 m1 = *reinterpret_cast<const int4*>(mrow + k0 + c0 + 32);
    const float4 e0 = *reinterpret_cast<const float4*>(ebase + k0 + c0);
    const float4 e1 = *reinterpret_cast<const float4*>(ebase + k0 + c0 + 32);
    dpart += (m0.x ? e0.x : 0.f) + (m0.y ? e0.y : 0.f)
           + (m0.z ? e0.z : 0.f) + (m0.w ? e0.w : 0.f)
           + (m1.x ? e1.x : 0.f) + (m1.y ? e1.y : 0.f)
           + (m1.z ? e1.z : 0.f) + (m1.w ? e1.w : 0.f);
    ushort4 a0, a1;
    a0.x = m0.x ? 0x3F80 : 0;  a0.y = m0.y ? 0x3F80 : 0;
    a0.z = m0.z ? 0x3F80 : 0;  a0.w = m0.w ? 0x3F80 : 0;
    a1.x = m1.x ? 0x3F80 : 0;  a1.y = m1.y ? 0x3F80 : 0;
    a1.z = m1.z ? 0x3F80 : 0;  a1.w = m1.w ? 0x3F80 : 0;
    *reinterpret_cast<ushort4*>(&A_s[sr * 64 + (c0 ^ swA)]) = a0;
    *reinterpret_cast<ushort4*>(&A_s[sr * 64 + ((c0 + 32) ^ swA)]) = a1;
    // ---- stage B: bf16 evT, 4 x 16B per thread ----
#pragma unroll
    for (int s = 0; s < 4; ++s) {
      const ushort8v bv = *reinterpret_cast<const ushort8v*>(evrow + k0 + bj + s * 8);
      *reinterpret_cast<ushort8v*>(&B_s[bd * 64 + ((bj + s * 8) ^ swB)]) = bv;
    }
    __syncthreads();
    // ---- compute: 16 MFMA / wave / K-tile ----
#pragma unroll
    for (int kk = 0; kk < 64; kk += 32) {
      const int kr = kk + ((lane >> 4) << 3);
      short8v af[2], bf[4];
#pragma unroll
      for (int m = 0; m < 2; ++m) {
        const int row = wm * 32 + m * 16 + (lane & 15);
        af[m] = *reinterpret_cast<const short8v*>(&A_s[row * 64 + (kr ^ ((row & 7) * 8))]);
      }
#pragma unroll
      for (int n = 0; n < 4; ++n) {
        const int d = wn * 64 + n * 16 + (lane & 15);
        bf[n] = *reinterpret_cast<const short8v*>(&B_s[d * 64 + (kr ^ ((d & 7) * 8))]);
      }
#pragma unroll
      for (int m = 0; m < 2; ++m)
#pragma unroll
        for (int n = 0; n < 4; ++n)
          acc[m][n] = __builtin_amdgcn_mfma_f32_16x16x32_bf16(af[m], bf[n], acc[m][n], 0, 0, 0);
    }
  }

  // ---- denominator: reduce the 8 staging threads of each row ----
  dpart += __shfl_xor(dpart, 4);
  dpart += __shfl_xor(dpart, 2);
  dpart += __shfl_xor(dpart, 1);
  if ((t & 7) == 0) denom_s[sr] = dpart;
  __syncthreads();

  // ---- epilogue: divide and store (C layout: col=lane&15, row=(lane>>4)*4+reg) --
#pragma unroll
  for (int m = 0; m < 2; ++m) {
    const int row0 = wm * 32 + m * 16 + ((lane >> 4) << 2);
    float inv[4];
#pragma unroll
    for (int r = 0; r < 4; ++r) {
      const float dn = denom_s[row0 + r];
      inv[r] = (dn == 0.f) ? 0.f : 1.f / dn;   // all-masked row: unreachable, avoid NaN
    }
#pragma unroll
    for (int n = 0; n < 4; ++n) {
      const int col = wn * 64 + n * 16 + (lane & 15);
#pragma unroll
      for (int r = 0; r < 4; ++r)
        out[((size_t)b * LQ + (i0 + row0 + r)) * DD + col] = acc[m][n][r] * inv[r];
    }
  }
}

extern "C" void kernel_launch(void* const* d_in, const int* in_sizes, int n_in,
                              void* d_out, int out_size, void* d_ws, size_t ws_size,
                              hipStream_t stream) {
  // inputs: 0=query (unused: softmax shift-invariance), 1=key, 2=value, 3=mask, 4=w_align
  const float* key   = (const float*)d_in[1];
  const float* value = (const float*)d_in[2];
  const int*   mask  = (const int*)d_in[3];
  const float* w     = (const float*)d_in[4];
  float* out = (float*)d_out;

  unsigned short* evT = (unsigned short*)d_ws;                      // 8 MB
  float* e_arr = (float*)((char*)d_ws + (size_t)NB * DD * LK * 2);  // 64 KB

  bah_precompute<<<NB * (LK / 64), 256, 0, stream>>>(key, value, w, evT, e_arr);
  bah_gemm<<<NB * (LQ / 64), 512, 0, stream>>>(mask, evT, e_arr, out);
}